// Round 7
// baseline (876.324 us; speedup 1.0000x reference)
//
#include <hip/hip_runtime.h>
#include <hip/hip_bf16.h>

// SCConv on MI355X. Shapes compile-time known:
// nodes 2048, edges 6144, faces 4096, C=128, 2 layers, out = (2,) f32.
//
// Strategy: the 7 neighborhood GEMMs per layer stream the fp32 neighborhood
// matrices (688 MB/layer -> memory-bound, floor ~109 us/layer) through a
// 128x128-tile mfma_f32_16x16x32_bf16 GEMM with on-the-fly fp32->bf16
// conversion during LDS staging. B = x@W precomputed in bf16, feature-major.
// fp32 accumulation across K-chunks via global atomicAdd. 1312 uniform
// ~0.8MB work units per layer (~5.1/CU). T14 async-stage (global->reg
// before MFMA phase, reg->LDS after barrier) hides HBM latency.
//
// Open risk (no profile yet): 21.5M epilogue atomics/layer could cost
// ~30-70us/layer. If first profile shows big_gemm dur >> FETCH/6.3TB/s with
// low MfmaUtil/VALUBusy -> pivot to per-kchunk slabs + reduce fused in sig.

typedef __bf16 bf16_t;
typedef __attribute__((ext_vector_type(8))) __bf16 bf16x8;
typedef __attribute__((ext_vector_type(4))) __bf16 bf16x4;
typedef __attribute__((ext_vector_type(4))) float f32x4;

#define MFMA(a, b, c) __builtin_amdgcn_mfma_f32_16x16x32_bf16(a, b, c, 0, 0, 0)
// XOR swizzle on LDS byte offsets: spreads stride-128B/256B rows across banks.
#define SWZ(row, cb) ((cb) ^ (((row) & 7) << 4))
// Trans-path swizzle: extra (k>>3) term separates k-groups {j,j+8,j+16,j+24}
// (which share k&7) into distinct 32B regions -> 2 lanes/bank on the u16
// gather instead of 8. XOR bits >=3 only => 8B-granular writes stay intact.
#define SWZT(k, cb) ((cb) ^ (((k) & 7) << 4) ^ ((((k) >> 3) & 3) << 5))

__device__ inline bf16x4 cvt4(f32x4 v) {
  bf16x4 r;
  r[0] = (bf16_t)v[0]; r[1] = (bf16_t)v[1];
  r[2] = (bf16_t)v[2]; r[3] = (bf16_t)v[3];
  return r;
}

// A-matrices are streamed exactly once per layer -> nontemporal (keep Bt/C in L2).
__device__ inline f32x4 ntld(const float* p) {
  return __builtin_nontemporal_load((const f32x4*)p);
}

struct GemmPair {
  const float* A;      // normal: M x K row-major (ldA=K); trans: K x M row-major (ldA=M)
  const bf16_t* Bt;    // x@W, stored TRANSPOSED: [128 features][K]
  float* C;            // M x 128 fp32 accumulator (atomicAdd)
  int K, ldA, trans, unitStart, nKC;
};
struct GemmArgs { GemmPair p[8]; };

struct XWJob { const float* x; const float* w; bf16_t* out; int M; int blkStart; };
struct XWArgs { XWJob j[7]; };

// ------------------------------------------- sigmoid (+ re-zero C for next layer)
__global__ void sig_kernel(float* __restrict__ c, float* __restrict__ x, int n4) {
  int i = blockIdx.x * 256 + threadIdx.x;
  if (i < n4) {
    f32x4 v = ((f32x4*)c)[i];
    f32x4 o;
#pragma unroll
    for (int r = 0; r < 4; r++) o[r] = 1.0f / (1.0f + __expf(-v[r]));
    ((f32x4*)x)[i] = o;
    f32x4 z = {0.f, 0.f, 0.f, 0.f};
    ((f32x4*)c)[i] = z;  // C ready for next layer's atomics (stays L2-resident)
  }
}

// ----------------------------------------------------- x @ W  (K=128, bf16 out, transposed)
__global__ __launch_bounds__(256, 2) void xw_kernel(XWArgs xa) {
  int blk = blockIdx.x;
  // conditional-overwrite chain on uniform scalars (no runtime kernarg indexing)
  XWJob J = xa.j[0];
#pragma unroll
  for (int i = 1; i < 7; i++)
    if (blk >= xa.j[i].blkStart) J = xa.j[i];
  long m0 = (long)(blk - J.blkStart) * 128;
  int tid = threadIdx.x, lane = tid & 63, wid = tid >> 6;
  int wr = wid >> 1, wc = wid & 1;

  __shared__ __align__(16) char Xs[32768];  // [m 128][c 128] bf16, 256B rows, swizzled
  __shared__ __align__(16) char Wt[32768];  // [n 128][c 128] bf16 (W transposed)

  // stage x (fp32 -> bf16)
#pragma unroll
  for (int j = 0; j < 16; j++) {
    int g = j * 256 + tid, row = g >> 5, c4 = g & 31;
    f32x4 v = *(const f32x4*)(J.x + (m0 + row) * 128 + c4 * 4);
    *(bf16x4*)(Xs + row * 256 + SWZ(row, c4 * 8)) = cvt4(v);
  }
  // stage W transposed (scatter u16 writes; once per block)
#pragma unroll
  for (int j = 0; j < 16; j++) {
    int g = j * 256 + tid, c = g >> 5, n4 = g & 31;
    f32x4 v = *(const f32x4*)(J.w + c * 128 + n4 * 4);
#pragma unroll
    for (int i = 0; i < 4; i++) {
      int n = n4 * 4 + i;
      *(bf16_t*)(Wt + n * 256 + SWZ(n, c * 2)) = (bf16_t)v[i];
    }
  }
  __syncthreads();

  f32x4 acc[4][4];
  f32x4 z = {0.f, 0.f, 0.f, 0.f};
#pragma unroll
  for (int a = 0; a < 4; a++)
#pragma unroll
    for (int b = 0; b < 4; b++) acc[a][b] = z;

#pragma unroll
  for (int kk = 0; kk < 4; kk++) {  // K=128 in steps of 32
    bf16x8 af[4], bfr[4];
#pragma unroll
    for (int mf = 0; mf < 4; mf++) {
      int row = wr * 64 + mf * 16 + (lane & 15);
      af[mf] = *(const bf16x8*)(Xs + row * 256 + SWZ(row, kk * 64 + (lane >> 4) * 16));
    }
#pragma unroll
    for (int nf = 0; nf < 4; nf++) {
      int n = wc * 64 + nf * 16 + (lane & 15);
      bfr[nf] = *(const bf16x8*)(Wt + n * 256 + SWZ(n, kk * 64 + (lane >> 4) * 16));
    }
#pragma unroll
    for (int mf = 0; mf < 4; mf++)
#pragma unroll
      for (int nf = 0; nf < 4; nf++)
        acc[mf][nf] = MFMA(af[mf], bfr[nf], acc[mf][nf]);
  }

  // store transposed: out[n][m]  (4 consecutive m -> one 8B store)
#pragma unroll
  for (int mf = 0; mf < 4; mf++)
#pragma unroll
    for (int nf = 0; nf < 4; nf++) {
      int n = wc * 64 + nf * 16 + (lane & 15);
      long m = m0 + wr * 64 + mf * 16 + ((lane >> 4) * 4);
      bf16x4 o;
#pragma unroll
      for (int r = 0; r < 4; r++) o[r] = (bf16_t)acc[mf][nf][r];
      *(bf16x4*)(J.out + (long)n * J.M + m) = o;
    }
}

// ------------------------------------------------------------- big GEMM
// unit = (pair, mblock of 128 rows, kchunk of 1024). BK=64, 4 waves 2x2.
__global__ __launch_bounds__(256, 2) void big_gemm(GemmArgs ga) {
  int u = blockIdx.x;
  GemmPair P = ga.p[0];
#pragma unroll
  for (int i = 1; i < 8; i++)
    if (u >= ga.p[i].unitStart) P = ga.p[i];
  int lu = u - P.unitStart;
  int mb = lu / P.nKC;
  int kc = lu - mb * P.nKC;
  long m0 = (long)mb * 128;
  long k0 = (long)kc * 1024;
  int tid = threadIdx.x, lane = tid & 63, wid = tid >> 6;
  int wr = wid >> 1, wc = wid & 1;

  __shared__ __align__(16) char Asm[16384];  // normal: [m 128][k 64]; trans: [k 64][m 128]
  __shared__ __align__(16) char Bsm[16384];  // [feat 128][k 64]

  f32x4 acc[4][4];
  f32x4 z = {0.f, 0.f, 0.f, 0.f};
#pragma unroll
  for (int a = 0; a < 4; a++)
#pragma unroll
    for (int b = 0; b < 4; b++) acc[a][b] = z;

  const bf16_t* Bb = P.Bt + k0;
  f32x4 ra[8];
  bf16x8 rb[4];

  if (!P.trans) {
    const float* Ab = P.A + m0 * P.ldA + k0;
    // prologue: load ks=0 into regs
#pragma unroll
    for (int j = 0; j < 8; j++) {
      int g = j * 256 + tid, row = g >> 4, c4 = g & 15;
      ra[j] = ntld(Ab + (long)row * P.ldA + c4 * 4);
    }
#pragma unroll
    for (int j = 0; j < 4; j++) {
      int g = j * 256 + tid, f = g >> 3, gc = g & 7;
      rb[j] = *(const bf16x8*)(Bb + (long)f * P.K + gc * 8);
    }
    for (int ks = 0; ks < 16; ++ks) {
      // write staged regs -> LDS (fp32->bf16 for A)
#pragma unroll
      for (int j = 0; j < 8; j++) {
        int g = j * 256 + tid, row = g >> 4, c4 = g & 15;
        *(bf16x4*)(Asm + row * 128 + SWZ(row, c4 * 8)) = cvt4(ra[j]);
      }
#pragma unroll
      for (int j = 0; j < 4; j++) {
        int g = j * 256 + tid, f = g >> 3, gc = g & 7;
        *(bf16x8*)(Bsm + f * 128 + SWZ(f, gc * 16)) = rb[j];
      }
      __syncthreads();
      // issue next K-step's loads BEFORE compute (hide HBM latency under MFMA)
      if (ks + 1 < 16) {
#pragma unroll
        for (int j = 0; j < 8; j++) {
          int g = j * 256 + tid, row = g >> 4, c4 = g & 15;
          ra[j] = ntld(Ab + (long)row * P.ldA + (ks + 1) * 64 + c4 * 4);
        }
#pragma unroll
        for (int j = 0; j < 4; j++) {
          int g = j * 256 + tid, f = g >> 3, gc = g & 7;
          rb[j] = *(const bf16x8*)(Bb + (long)f * P.K + (ks + 1) * 64 + gc * 8);
        }
      }
#pragma unroll
      for (int kk = 0; kk < 2; kk++) {
        bf16x8 af[4], bfr[4];
#pragma unroll
        for (int mf = 0; mf < 4; mf++) {
          int row = wr * 64 + mf * 16 + (lane & 15);
          af[mf] = *(const bf16x8*)(Asm + row * 128 + SWZ(row, kk * 64 + (lane >> 4) * 16));
        }
#pragma unroll
        for (int nf = 0; nf < 4; nf++) {
          int f = wc * 64 + nf * 16 + (lane & 15);
          bfr[nf] = *(const bf16x8*)(Bsm + f * 128 + SWZ(f, kk * 64 + (lane >> 4) * 16));
        }
#pragma unroll
        for (int mf = 0; mf < 4; mf++)
#pragma unroll
          for (int nf = 0; nf < 4; nf++)
            acc[mf][nf] = MFMA(af[mf], bfr[nf], acc[mf][nf]);
      }
      __syncthreads();
    }
    // epilogue: atomic accumulate into C[M][128]
#pragma unroll
    for (int mf = 0; mf < 4; mf++)
#pragma unroll
      for (int nf = 0; nf < 4; nf++) {
        long row = m0 + wr * 64 + mf * 16 + ((lane >> 4) * 4);
        int col = wc * 64 + nf * 16 + (lane & 15);
        float* Cp = P.C + row * 128 + col;
#pragma unroll
        for (int r = 0; r < 4; r++) atomicAdd(Cp + r * 128, acc[mf][nf][r]);
      }
  } else {
    // out = Astored^T @ B. Compute out^T via swapped operands:
    // mfma-A = Bt fragments (feature rows), mfma-B = Astored natural [k][m].
    const float* At = P.A + k0 * P.ldA + m0;
#pragma unroll
    for (int j = 0; j < 8; j++) {
      int g = j * 256 + tid, kr = g >> 5, c4 = g & 31;
      ra[j] = ntld(At + (long)kr * P.ldA + c4 * 4);
    }
#pragma unroll
    for (int j = 0; j < 4; j++) {
      int g = j * 256 + tid, f = g >> 3, gc = g & 7;
      rb[j] = *(const bf16x8*)(Bb + (long)f * P.K + gc * 8);
    }
    for (int ks = 0; ks < 16; ++ks) {
#pragma unroll
      for (int j = 0; j < 8; j++) {
        int g = j * 256 + tid, kr = g >> 5, c4 = g & 31;
        *(bf16x4*)(Asm + kr * 256 + SWZT(kr, c4 * 8)) = cvt4(ra[j]);
      }
#pragma unroll
      for (int j = 0; j < 4; j++) {
        int g = j * 256 + tid, f = g >> 3, gc = g & 7;
        *(bf16x8*)(Bsm + f * 128 + SWZ(f, gc * 16)) = rb[j];
      }
      __syncthreads();
      if (ks + 1 < 16) {
#pragma unroll
        for (int j = 0; j < 8; j++) {
          int g = j * 256 + tid, kr = g >> 5, c4 = g & 31;
          ra[j] = ntld(At + (long)((ks + 1) * 64 + kr) * P.ldA + c4 * 4);
        }
#pragma unroll
        for (int j = 0; j < 4; j++) {
          int g = j * 256 + tid, f = g >> 3, gc = g & 7;
          rb[j] = *(const bf16x8*)(Bb + (long)f * P.K + (ks + 1) * 64 + gc * 8);
        }
      }
#pragma unroll
      for (int kk = 0; kk < 2; kk++) {
        bf16x8 af[4], bg[4];
#pragma unroll
        for (int nf = 0; nf < 4; nf++) {
          int f = wr * 64 + nf * 16 + (lane & 15);
          af[nf] = *(const bf16x8*)(Bsm + f * 128 + SWZ(f, kk * 64 + (lane >> 4) * 16));
        }
#pragma unroll
        for (int mf = 0; mf < 4; mf++) {
          int m2 = (wc * 64 + mf * 16 + (lane & 15)) * 2;
#pragma unroll
          for (int jj = 0; jj < 8; jj++) {
            int k = kk * 32 + (lane >> 4) * 8 + jj;
            bg[mf][jj] = *(const bf16_t*)(Asm + k * 256 + SWZT(k, m2));
          }
        }
#pragma unroll
        for (int nf = 0; nf < 4; nf++)
#pragma unroll
          for (int mf = 0; mf < 4; mf++)
            acc[nf][mf] = MFMA(af[nf], bg[mf], acc[nf][mf]);
      }
      __syncthreads();
    }
    // epilogue: D[i=feat][j=m]; 4 regs = 4 consecutive feats of one m-row
#pragma unroll
    for (int nf = 0; nf < 4; nf++)
#pragma unroll
      for (int mf = 0; mf < 4; mf++) {
        long m = m0 + wc * 64 + mf * 16 + (lane & 15);
        int n = wr * 64 + nf * 16 + ((lane >> 4) * 4);
        float* Cp = P.C + m * 128 + n;
#pragma unroll
        for (int r = 0; r < 4; r++) atomicAdd(Cp + r, acc[nf][mf][r]);
      }
  }
}

// ---------------------------------------------------------------- heads
__global__ __launch_bounds__(256) void colsum_kernel(const float* __restrict__ x,
                                                     float* __restrict__ colsum) {
  int row0 = blockIdx.x * 64;  // 12288 rows / 64 = 192 blocks; rank boundaries are x64
  int c = threadIdx.x & 127, half = threadIdx.x >> 7;
  float s = 0.f;
#pragma unroll 4
  for (int i = 0; i < 32; i++) {
    int r = row0 + half * 32 + i;
    s += x[(long)r * 128 + c];
  }
  __shared__ float sm[256];
  sm[threadIdx.x] = s;
  __syncthreads();
  if (half == 0) {
    float tot = s + sm[128 + threadIdx.x];
    int rank = row0 < 2048 ? 0 : (row0 < 8192 ? 1 : 2);
    atomicAdd(&colsum[rank * 128 + c], tot);
  }
}

__global__ void final_kernel(const float* __restrict__ colsum,
                             const float* l0w, const float* l0b,
                             const float* l1w, const float* l1b,
                             const float* l2w, const float* l2b,
                             float* __restrict__ out) {
  int j = threadIdx.x;
  if (j < 2) {
    float acc = l0b[j] + l1b[j] + l2b[j];
    for (int c = 0; c < 128; c++) {
      acc += colsum[c]       * (1.f / 2048.f) * l0w[c * 2 + j];
      acc += colsum[128 + c] * (1.f / 6144.f) * l1w[c * 2 + j];
      acc += colsum[256 + c] * (1.f / 4096.f) * l2w[c * 2 + j];
    }
    out[j] = acc;
  }
}

// ---------------------------------------------------------------- launch
extern "C" void kernel_launch(void* const* d_in, const int* in_sizes, int n_in,
                              void* d_out, int out_size, void* d_ws, size_t ws_size,
                              hipStream_t stream) {
  (void)in_sizes; (void)n_in; (void)out_size; (void)ws_size;
  const float* x0i  = (const float*)d_in[0];
  const float* x1i  = (const float*)d_in[1];
  const float* x2i  = (const float*)d_in[2];
  const float* inc1  = (const float*)d_in[3];
  const float* inc1n = (const float*)d_in[4];
  const float* inc2  = (const float*)d_in[5];
  const float* inc2n = (const float*)d_in[6];
  const float* au0 = (const float*)d_in[7];
  const float* au1 = (const float*)d_in[8];
  const float* ad1 = (const float*)d_in[9];
  const float* ad2 = (const float*)d_in[10];
  const float* W00 = (const float*)d_in[11];
  const float* W10 = (const float*)d_in[12];
  const float* W01 = (const float*)d_in[13];
  const float* W11 = (const float*)d_in[14];
  const float* W21 = (const float*)d_in[15];
  const float* W12 = (const float*)d_in[16];
  const float* W22 = (const float*)d_in[17];
  const float* l0w = (const float*)d_in[18];
  const float* l0b = (const float*)d_in[19];
  const float* l1w = (const float*)d_in[20];
  const float* l1b = (const float*)d_in[21];
  const float* l2w = (const float*)d_in[22];
  const float* l2b = (const float*)d_in[23];

  // workspace layout (floats): C[12288*128] colsum[512] xA[12288*128] xB[12288*128] XWt(bf16)
  float* C = (float*)d_ws;
  float* colsum = C + (size_t)12288 * 128;
  float* xA = colsum + 512;
  float* xB = xA + (size_t)12288 * 128;
  bf16_t* t0 = (bf16_t*)(xB + (size_t)12288 * 128);
  bf16_t* t1 = t0 + (size_t)2048 * 128;
  bf16_t* u0 = t1 + (size_t)6144 * 128;
  bf16_t* u1 = u0 + (size_t)2048 * 128;
  bf16_t* u2 = u1 + (size_t)6144 * 128;
  bf16_t* v1 = u2 + (size_t)4096 * 128;
  bf16_t* v2 = v1 + (size_t)6144 * 128;

  float* C0 = C;
  float* C1 = C + (size_t)2048 * 128;
  float* C2 = C + (size_t)8192 * 128;

  GemmArgs ga;  // identical for both layers (only Bt *contents* change)
  // units per pair = (M/128) * (K/1024)
  ga.p[0] = { au0,   t0, C0, 2048, 2048, 0, 0,    2 };  // 16*2  = 32
  ga.p[1] = { inc1n, t1, C0, 6144, 6144, 0, 32,   6 };  // 16*6  = 96
  ga.p[2] = { inc1,  u0, C1, 2048, 6144, 1, 128,  2 };  // 48*2  = 96  (inc1^T)
  ga.p[3] = { ad1,   u1, C1, 6144, 6144, 0, 224,  6 };  // 48*6  = 288
  ga.p[4] = { au1,   u1, C1, 6144, 6144, 0, 512,  6 };  // 48*6  = 288
  ga.p[5] = { inc2n, u2, C1, 4096, 4096, 0, 800,  4 };  // 48*4  = 192
  ga.p[6] = { inc2,  v1, C2, 6144, 4096, 1, 992,  6 };  // 32*6  = 192 (inc2^T)
  ga.p[7] = { ad2,   v2, C2, 4096, 4096, 0, 1184, 4 };  // 32*4  = 128
  // total units: 1312

  // one-time zero of C + colsum (C re-zeroed by sig_kernel thereafter)
  hipMemsetAsync(C, 0, (size_t)(12288 * 128 + 512) * 4, stream);

  for (int l = 0; l < 2; ++l) {
    const float* lx0 = l ? xA : x0i;
    const float* lx1 = l ? xA + (size_t)2048 * 128 : x1i;
    const float* lx2 = l ? xA + (size_t)8192 * 128 : x2i;
    int wo = l * 128 * 128;
    XWArgs xa;
    xa.j[0] = { lx0, W00 + wo, t0, 2048, 0   };
    xa.j[1] = { lx1, W10 + wo, t1, 6144, 16  };
    xa.j[2] = { lx0, W01 + wo, u0, 2048, 64  };
    xa.j[3] = { lx1, W11 + wo, u1, 6144, 80  };
    xa.j[4] = { lx2, W21 + wo, u2, 4096, 128 };
    xa.j[5] = { lx1, W12 + wo, v1, 6144, 160 };
    xa.j[6] = { lx2, W22 + wo, v2, 4096, 208 };
    // total blocks: 240

    hipLaunchKernelGGL(xw_kernel, dim3(240), dim3(256), 0, stream, xa);
    hipLaunchKernelGGL(big_gemm, dim3(1312), dim3(256), 0, stream, ga);
    hipLaunchKernelGGL(sig_kernel, dim3(1536), dim3(256), 0, stream, C, l ? xB : xA, 393216);
  }
  hipLaunchKernelGGL(colsum_kernel, dim3(192), dim3(256), 0, stream, xB, colsum);
  hipLaunchKernelGGL(final_kernel, dim3(1), dim3(64), 0, stream, colsum,
                     l0w, l0b, l1w, l1b, l2w, l2b, (float*)d_out);
}